// Round 7
// baseline (752.890 us; speedup 1.0000x reference)
//
#include <hip/hip_runtime.h>
#include <hip/hip_bf16.h>
#include <math.h>

#define N_NODES 190464
#define NPG 186
#define NGRAPH 1024
#define CAP 4096
#define KW 62
#define OCH 8
#define TOUT 125
#define BCHUNK 4096
#define NBLK 744   // 744 * 4096 == 3047424 == E

// ---------- helpers ----------
__device__ __forceinline__ float lrelu2(float v) { return v > 0.f ? v : 0.2f * v; }

// ---------- 1. BN batch statistics ----------
__global__ __launch_bounds__(256) void bn_stats(const float* __restrict__ x,
                                                double* __restrict__ stats) {
    double s[5] = {0, 0, 0, 0, 0}, ss[5] = {0, 0, 0, 0, 0};
    int stride = gridDim.x * blockDim.x;
    for (int n = blockIdx.x * blockDim.x + threadIdx.x; n < N_NODES; n += stride) {
#pragma unroll
        for (int f = 0; f < 5; ++f) {
            float v = x[n * 5 + f];
            s[f] += v;
            ss[f] += (double)v * (double)v;
        }
    }
#pragma unroll
    for (int f = 0; f < 5; ++f) {
        for (int off = 32; off; off >>= 1) {
            s[f] += __shfl_down(s[f], off);
            ss[f] += __shfl_down(ss[f], off);
        }
    }
    if ((threadIdx.x & 63) == 0) {
#pragma unroll
        for (int f = 0; f < 5; ++f) {
            unsafeAtomicAdd(&stats[f], s[f]);
            unsafeAtomicAdd(&stats[5 + f], ss[f]);
        }
    }
}

// ---------- 2. prep: fold BN into lin_w, fold att through wn, pad conv_w ----------
// prm layout (floats): wn[480]@0, hb[96]@480, as_w[20]@576, as_b[4]@596,
//                      ad_w[20]@600, ad_b[4]@620   (total 624)
__global__ void prep(const double* __restrict__ stats,
                     const float* __restrict__ gamma,
                     const float* __restrict__ beta,
                     const float* __restrict__ lin_w,
                     const float* __restrict__ att_src,
                     const float* __restrict__ att_dst,
                     const float* __restrict__ conv_w,
                     float* __restrict__ prm,
                     float* __restrict__ wpad) {
    __shared__ float scale[5], shift[5];
    int t = threadIdx.x;
    if (t < 5) {
        double mu = stats[t] / (double)N_NODES;
        double var = stats[5 + t] / (double)N_NODES - mu * mu;
        double rstd = 1.0 / sqrt(var + 1e-5);
        float sc = (float)rstd * gamma[t];
        scale[t] = sc;
        shift[t] = beta[t] - (float)mu * sc;
    }
    __syncthreads();
    if (t < 96) {
        float hbv = 0.f;
#pragma unroll
        for (int f = 0; f < 5; ++f) {
            float w = lin_w[t * 5 + f];
            prm[t * 5 + f] = w * scale[f];
            hbv += w * shift[f];
        }
        prm[480 + t] = hbv;
    }
    __syncthreads();
    if (t < 8) {
        int h = t & 3;
        const float* att = (t < 4) ? att_src : att_dst;
        int wb = (t < 4) ? 576 : 600;
        int bb = (t < 4) ? 596 : 620;
        float bsum = 0.f;
        float wsum[5] = {0, 0, 0, 0, 0};
        for (int c = 0; c < 24; ++c) {
            float a = att[h * 24 + c];
            int o = h * 24 + c;
#pragma unroll
            for (int f = 0; f < 5; ++f) wsum[f] += a * prm[o * 5 + f];
            bsum += a * prm[480 + o];
        }
#pragma unroll
        for (int f = 0; f < 5; ++f) prm[wb + h * 5 + f] = wsum[f];
        prm[bb + h] = bsum;
    }
    // pad conv weights [8*24][62] -> [8*24][64] (zeros at k=62,63)
    for (int i = t; i < OCH * 24 * 64; i += 256) {
        int k = i & 63, oi = i >> 6;
        wpad[i] = (k < KW) ? conv_w[oi * KW + k] : 0.f;
    }
}

// ---------- 3. hierarchical bucket-by-graph: LDS hist -> 1 global atomic ----------
__global__ __launch_bounds__(256) void bucket_pairs(const int* __restrict__ ei,
                                                    const int E,
                                                    int* __restrict__ gcnt,
                                                    unsigned* __restrict__ pairbuf) {
    __shared__ int h[NGRAPH];
    int tid = threadIdx.x;
    int e0 = blockIdx.x * BCHUNK;
#pragma unroll
    for (int i = tid; i < NGRAPH; i += 256) h[i] = 0;
    __syncthreads();
    // pass 1: LDS histogram of dst graphs
    for (int i = tid; i < BCHUNK; i += 256) {
        int dst = ei[E + e0 + i];
        unsigned g = (unsigned)dst / NPG;
        atomicAdd(&h[g], 1);
    }
    __syncthreads();
    // reserve contiguous slots per graph with ONE global atomic each
    for (int g = tid; g < NGRAPH; g += 256) {
        int c = h[g];
        h[g] = c ? atomicAdd(&gcnt[g], c) : 0;   // h[g] becomes cursor base
    }
    __syncthreads();
    // pass 2: scatter with LDS cursors (L2-hot re-read)
    for (int i = tid; i < BCHUNK; i += 256) {
        int src = ei[e0 + i];
        int dst = ei[E + e0 + i];
        unsigned g = (unsigned)dst / NPG;
        int dloc = dst - (int)g * NPG;
        int pos = atomicAdd(&h[g], 1);
        if (pos < CAP)
            pairbuf[(size_t)g * CAP + pos] = (unsigned)src | ((unsigned)dloc << 18);
    }
}

// ---------- 4. per-graph GAT: LDS counting sort + x-space accumulation ----------
__global__ __launch_bounds__(256) void gat_graph(
    const unsigned* __restrict__ pairbuf, const int* __restrict__ gcnt,
    const float* __restrict__ x, const float* __restrict__ prm,
    const float* __restrict__ gat_bias, float* __restrict__ gout) {
    __shared__ unsigned pair_s[CAP];
    __shared__ unsigned lsrc[CAP];
    __shared__ float xg[NPG * 5];
    __shared__ int deg[188];
    __shared__ int rp[188];
    __shared__ int cur[188];
    __shared__ int ts[256];
    __shared__ float prms[624];
    __shared__ float gb[24];

    int g = blockIdx.x, tid = threadIdx.x;
    int ne = min(gcnt[g], CAP);

    for (int i = tid; i < 624; i += 256) prms[i] = prm[i];
    if (tid < 24) gb[tid] = gat_bias[tid];
    for (int i = tid; i < NPG * 5; i += 256) xg[i] = x[(size_t)g * (NPG * 5) + i];
    if (tid < 188) deg[tid] = 0;
    __syncthreads();

    // stage + histogram
    for (int i = tid; i < ne; i += 256) {
        unsigned e = pairbuf[(size_t)g * CAP + i];
        pair_s[i] = e;
        atomicAdd(&deg[e >> 18], 1);
    }
    __syncthreads();

    // exclusive scan of 186 degrees (Hillis-Steele over 256 threads)
    int v = (tid < NPG) ? deg[tid] : 0;
    ts[tid] = v;
    __syncthreads();
    for (int off = 1; off < 256; off <<= 1) {
        int u = (tid >= off) ? ts[tid - off] : 0;
        __syncthreads();
        ts[tid] += u;
        __syncthreads();
    }
    if (tid < NPG) { rp[tid] = ts[tid] - v; cur[tid] = ts[tid] - v; }
    if (tid == NPG - 1) rp[NPG] = ts[tid];
    __syncthreads();

    // scatter into per-dst runs
    for (int i = tid; i < ne; i += 256) {
        unsigned e = pair_s[i];
        int dl = e >> 18;
        int pos = atomicAdd(&cur[dl], 1);
        lsrc[pos] = e & 0x3FFFFu;
    }
    __syncthreads();

    // compute: quad (4 lanes = 4 heads) per node
    int q = tid >> 2, h = tid & 3;
    const float* asw = &prms[576];
    const float* asb = &prms[596];
    const float* adw = &prms[600];
    const float* adb = &prms[620];
    float aw[5], dw[5];
#pragma unroll
    for (int f = 0; f < 5; ++f) { aw[f] = asw[h * 5 + f]; dw[f] = adw[h * 5 + f]; }
    float ab = asb[h], db = adb[h];

    for (int nl = q; nl < NPG; nl += 64) {
        float xd[5];
#pragma unroll
        for (int f = 0; f < 5; ++f) xd[f] = xg[nl * 5 + f];
        float ad = db, as = ab;
#pragma unroll
        for (int f = 0; f < 5; ++f) { ad += dw[f] * xd[f]; as += aw[f] * xd[f]; }
        // self-loop
        float e = __expf(lrelu2(as + ad));
        float denom = e;
        float ax[5];
#pragma unroll
        for (int f = 0; f < 5; ++f) ax[f] = e * xd[f];
        // in-edges
        int b = rp[nl], en = rp[nl + 1];
        for (int i = b; i < en; ++i) {
            int s = lsrc[i];
            const float* xp = x + (size_t)s * 5;
            float xs[5];
#pragma unroll
            for (int f = 0; f < 5; ++f) xs[f] = xp[f];
            float a2 = ab;
#pragma unroll
            for (int f = 0; f < 5; ++f) a2 += aw[f] * xs[f];
            float ee = __expf(lrelu2(a2 + ad));
            denom += ee;
#pragma unroll
            for (int f = 0; f < 5; ++f) ax[f] += ee * xs[f];
        }
        float inv = 1.f / (denom + 1e-16f);
#pragma unroll
        for (int f = 0; f < 5; ++f) ax[f] *= inv;
        // expand to 24 channels, head-mean via quad shuffle, bias + ELU
        float* go = gout + ((size_t)g * NPG + nl) * 24;
#pragma unroll
        for (int c = 0; c < 24; ++c) {
            int o = h * 24 + c;
            float vv = prms[480 + o];
#pragma unroll
            for (int f = 0; f < 5; ++f) vv += prms[o * 5 + f] * ax[f];
            vv *= 0.25f;
            vv += __shfl_xor(vv, 1);
            vv += __shfl_xor(vv, 2);
            if ((c & 3) == h) {
                vv += gb[c];
                go[c] = vv > 0.f ? vv : expm1f(vv);
            }
        }
    }
}

// ---------- 5. per-graph Conv1d(24->8, k=62) + leaky_relu ----------
// Wave w owns rows {w, w+4, ..., w+20}; half-wave owns 4 output channels.
// Weights read from global (L2-resident, half-wave-uniform b128 loads).
// LDS = input tile only (18.8 KB) -> 4 blocks/CU resident, 16 waves/CU.
__global__ __launch_bounds__(256, 4) void conv_k(
    const float* __restrict__ gat, const float* __restrict__ wpad,
    const float* __restrict__ b, float* __restrict__ out) {
    __shared__ float smem[24 * 196];   // it[c][p] @ smem[c*196+p]; reused for partials
    int g = blockIdx.x, tid = threadIdx.x;
    // stage node features transposed: it[c][p] = gat[g*186+p][c]
    for (int i = tid; i < NPG * 24; i += 256) {
        int p = i / 24, c = i % 24;
        smem[c * 196 + p] = gat[(size_t)g * (NPG * 24) + i];
    }
    for (int i = tid; i < 24 * 10; i += 256) {   // zero pad cols 186..195
        int c = i / 10;
        smem[c * 196 + 186 + (i % 10)] = 0.f;
    }
    __syncthreads();

    int w = tid >> 6;           // wave id: rows w, w+4, ..., w+20
    int l = tid & 63;
    int h2 = l >> 5;            // o-base = 4*h2
    int tt = l & 31;
    int t0 = tt * 4;

    float a[4][4];
#pragma unroll
    for (int oo = 0; oo < 4; ++oo)
#pragma unroll
        for (int j = 0; j < 4; ++j) a[oo][j] = 0.f;

#pragma unroll
    for (int r = 0; r < 6; ++r) {
        int i = w + r * 4;
        const float4* irow = (const float4*)&smem[i * 196 + t0];
        float4 win[17];
#pragma unroll
        for (int s = 0; s < 17; ++s) win[s] = irow[s];
#pragma unroll
        for (int oo = 0; oo < 4; ++oo) {
            const float4* wr4 = (const float4*)&wpad[(size_t)((4 * h2 + oo) * 24 + i) * 64];
#pragma unroll
            for (int s = 0; s < 16; ++s) {
                float4 wv = wr4[s];
                float4 c0 = win[s], c1 = win[s + 1];
                a[oo][0] += wv.x * c0.x + wv.y * c0.y + wv.z * c0.z + wv.w * c0.w;
                a[oo][1] += wv.x * c0.y + wv.y * c0.z + wv.z * c0.w + wv.w * c1.x;
                a[oo][2] += wv.x * c0.z + wv.y * c0.w + wv.z * c1.x + wv.w * c1.y;
                a[oo][3] += wv.x * c0.w + wv.y * c1.x + wv.z * c1.y + wv.w * c1.z;
            }
        }
    }
    __syncthreads();
    // partials: smem[w*1024 + o*128 + t]
#pragma unroll
    for (int oo = 0; oo < 4; ++oo) {
        float4 v = make_float4(a[oo][0], a[oo][1], a[oo][2], a[oo][3]);
        *(float4*)&smem[w * 1024 + (4 * h2 + oo) * 128 + t0] = v;
    }
    __syncthreads();
    // cross-wave reduction + bias + leaky_relu + store
    for (int idx = tid; idx < OCH * TOUT; idx += 256) {
        int o = idx / TOUT, t = idx - o * TOUT;
        int base = o * 128 + t;
        float s = smem[base] + smem[1024 + base] + smem[2048 + base] +
                  smem[3072 + base] + b[o];
        out[(size_t)g * (OCH * TOUT) + idx] = s > 0.f ? s : 0.01f * s;
    }
}

extern "C" void kernel_launch(void* const* d_in, const int* in_sizes, int n_in,
                              void* d_out, int out_size, void* d_ws, size_t ws_size,
                              hipStream_t stream) {
    const float* x        = (const float*)d_in[0];
    const int*   ei       = (const int*)d_in[1];
    const float* bn_gamma = (const float*)d_in[3];
    const float* bn_beta  = (const float*)d_in[4];
    const float* lin_w    = (const float*)d_in[5];
    const float* att_src  = (const float*)d_in[6];
    const float* att_dst  = (const float*)d_in[7];
    const float* gat_bias = (const float*)d_in[8];
    const float* conv_w   = (const float*)d_in[9];
    const float* conv_b   = (const float*)d_in[10];
    float* out = (float*)d_out;
    float* wsf = (float*)d_ws;
    int*   wsi = (int*)d_ws;

    const int E = in_sizes[1] / 2;

    // ws layout (4-byte units):
    // [0..64)            stats: double sum[5]+sumsq[5]
    // [64..1088)         gcnt: 1024 ints
    // [1088..1712)       prm: 624 floats
    // [1712..14000)      wpad: 8*24*64 floats (padded conv weights)
    // [14000..)          pairbuf: 1024*4096 packed (src|dloc<<18)
    // then               gout: N*24 floats
    int*      gcnt    = wsi + 64;
    float*    prm     = wsf + 1088;
    float*    wpad    = wsf + 1712;
    unsigned* pairbuf = (unsigned*)(wsi + 14000);
    float*    gout    = (float*)(pairbuf + (size_t)NGRAPH * CAP);

    // zero stats + gcnt in one contiguous memset (4352 B)
    hipMemsetAsync(d_ws, 0, (64 + NGRAPH) * 4, stream);

    bn_stats<<<256, 256, 0, stream>>>(x, (double*)wsf);
    prep<<<1, 256, 0, stream>>>((const double*)wsf, bn_gamma, bn_beta, lin_w,
                                att_src, att_dst, conv_w, prm, wpad);
    bucket_pairs<<<NBLK, 256, 0, stream>>>(ei, E, gcnt, pairbuf);
    gat_graph<<<NGRAPH, 256, 0, stream>>>(pairbuf, gcnt, x, prm, gat_bias, gout);
    conv_k<<<NGRAPH, 256, 0, stream>>>(gout, wpad, conv_b, out);
}

// Round 8
// 359.608 us; speedup vs baseline: 2.0936x; 2.0936x over previous
//
#include <hip/hip_runtime.h>
#include <hip/hip_bf16.h>
#include <math.h>

#define N_NODES 190464
#define NPG 186
#define NGRAPH 1024
#define CAP 4096
#define KW 62
#define OCH 8
#define TOUT 125
#define BCHUNK 4096
#define NBLK 744   // 744 * 4096 == 3047424 == E

// LDS column swizzle: banks for lanes 32-words apart become distinct.
// Preserves bits 0..1 (16B alignment) and stays within [0,196) for p<=191.
#define SWZ(p) ((p) ^ ((((p) >> 5) & 3) << 2))

// ---------- helpers ----------
__device__ __forceinline__ float lrelu2(float v) { return v > 0.f ? v : 0.2f * v; }

// ---------- 1. BN batch statistics ----------
__global__ __launch_bounds__(256) void bn_stats(const float* __restrict__ x,
                                                double* __restrict__ stats) {
    double s[5] = {0, 0, 0, 0, 0}, ss[5] = {0, 0, 0, 0, 0};
    int stride = gridDim.x * blockDim.x;
    for (int n = blockIdx.x * blockDim.x + threadIdx.x; n < N_NODES; n += stride) {
#pragma unroll
        for (int f = 0; f < 5; ++f) {
            float v = x[n * 5 + f];
            s[f] += v;
            ss[f] += (double)v * (double)v;
        }
    }
#pragma unroll
    for (int f = 0; f < 5; ++f) {
        for (int off = 32; off; off >>= 1) {
            s[f] += __shfl_down(s[f], off);
            ss[f] += __shfl_down(ss[f], off);
        }
    }
    if ((threadIdx.x & 63) == 0) {
#pragma unroll
        for (int f = 0; f < 5; ++f) {
            unsafeAtomicAdd(&stats[f], s[f]);
            unsafeAtomicAdd(&stats[5 + f], ss[f]);
        }
    }
}

// ---------- 2. prep: fold BN into lin_w, fold att through wn, pad conv_w ----------
// prm layout (floats): wn[480]@0, hb[96]@480, as_w[20]@576, as_b[4]@596,
//                      ad_w[20]@600, ad_b[4]@620   (total 624)
__global__ void prep(const double* __restrict__ stats,
                     const float* __restrict__ gamma,
                     const float* __restrict__ beta,
                     const float* __restrict__ lin_w,
                     const float* __restrict__ att_src,
                     const float* __restrict__ att_dst,
                     const float* __restrict__ conv_w,
                     float* __restrict__ prm,
                     float* __restrict__ wpad) {
    __shared__ float scale[5], shift[5];
    int t = threadIdx.x;
    if (t < 5) {
        double mu = stats[t] / (double)N_NODES;
        double var = stats[5 + t] / (double)N_NODES - mu * mu;
        double rstd = 1.0 / sqrt(var + 1e-5);
        float sc = (float)rstd * gamma[t];
        scale[t] = sc;
        shift[t] = beta[t] - (float)mu * sc;
    }
    __syncthreads();
    if (t < 96) {
        float hbv = 0.f;
#pragma unroll
        for (int f = 0; f < 5; ++f) {
            float w = lin_w[t * 5 + f];
            prm[t * 5 + f] = w * scale[f];
            hbv += w * shift[f];
        }
        prm[480 + t] = hbv;
    }
    __syncthreads();
    if (t < 8) {
        int h = t & 3;
        const float* att = (t < 4) ? att_src : att_dst;
        int wb = (t < 4) ? 576 : 600;
        int bb = (t < 4) ? 596 : 620;
        float bsum = 0.f;
        float wsum[5] = {0, 0, 0, 0, 0};
        for (int c = 0; c < 24; ++c) {
            float a = att[h * 24 + c];
            int o = h * 24 + c;
#pragma unroll
            for (int f = 0; f < 5; ++f) wsum[f] += a * prm[o * 5 + f];
            bsum += a * prm[480 + o];
        }
#pragma unroll
        for (int f = 0; f < 5; ++f) prm[wb + h * 5 + f] = wsum[f];
        prm[bb + h] = bsum;
    }
    // pad conv weights [8*24][62] -> [8*24][64] (zeros at k=62,63)
    for (int i = t; i < OCH * 24 * 64; i += 256) {
        int k = i & 63, oi = i >> 6;
        wpad[i] = (k < KW) ? conv_w[oi * KW + k] : 0.f;
    }
}

// ---------- 3. hierarchical bucket-by-graph: LDS hist -> 1 global atomic ----------
__global__ __launch_bounds__(256) void bucket_pairs(const int* __restrict__ ei,
                                                    const int E,
                                                    int* __restrict__ gcnt,
                                                    unsigned* __restrict__ pairbuf) {
    __shared__ int h[NGRAPH];
    int tid = threadIdx.x;
    int e0 = blockIdx.x * BCHUNK;
#pragma unroll
    for (int i = tid; i < NGRAPH; i += 256) h[i] = 0;
    __syncthreads();
    // pass 1: LDS histogram of dst graphs
    for (int i = tid; i < BCHUNK; i += 256) {
        int dst = ei[E + e0 + i];
        unsigned g = (unsigned)dst / NPG;
        atomicAdd(&h[g], 1);
    }
    __syncthreads();
    // reserve contiguous slots per graph with ONE global atomic each
    for (int g = tid; g < NGRAPH; g += 256) {
        int c = h[g];
        h[g] = c ? atomicAdd(&gcnt[g], c) : 0;   // h[g] becomes cursor base
    }
    __syncthreads();
    // pass 2: scatter with LDS cursors (L2-hot re-read)
    for (int i = tid; i < BCHUNK; i += 256) {
        int src = ei[e0 + i];
        int dst = ei[E + e0 + i];
        unsigned g = (unsigned)dst / NPG;
        int dloc = dst - (int)g * NPG;
        int pos = atomicAdd(&h[g], 1);
        if (pos < CAP)
            pairbuf[(size_t)g * CAP + pos] = (unsigned)src | ((unsigned)dloc << 18);
    }
}

// ---------- 4. per-graph GAT: LDS counting sort + x-space accumulation ----------
__global__ __launch_bounds__(256) void gat_graph(
    const unsigned* __restrict__ pairbuf, const int* __restrict__ gcnt,
    const float* __restrict__ x, const float* __restrict__ prm,
    const float* __restrict__ gat_bias, float* __restrict__ gout) {
    __shared__ unsigned pair_s[CAP];
    __shared__ unsigned lsrc[CAP];
    __shared__ float xg[NPG * 5];
    __shared__ int deg[188];
    __shared__ int rp[188];
    __shared__ int cur[188];
    __shared__ int ts[256];
    __shared__ float prms[624];
    __shared__ float gb[24];

    int g = blockIdx.x, tid = threadIdx.x;
    int ne = min(gcnt[g], CAP);

    for (int i = tid; i < 624; i += 256) prms[i] = prm[i];
    if (tid < 24) gb[tid] = gat_bias[tid];
    for (int i = tid; i < NPG * 5; i += 256) xg[i] = x[(size_t)g * (NPG * 5) + i];
    if (tid < 188) deg[tid] = 0;
    __syncthreads();

    // stage + histogram
    for (int i = tid; i < ne; i += 256) {
        unsigned e = pairbuf[(size_t)g * CAP + i];
        pair_s[i] = e;
        atomicAdd(&deg[e >> 18], 1);
    }
    __syncthreads();

    // exclusive scan of 186 degrees (Hillis-Steele over 256 threads)
    int v = (tid < NPG) ? deg[tid] : 0;
    ts[tid] = v;
    __syncthreads();
    for (int off = 1; off < 256; off <<= 1) {
        int u = (tid >= off) ? ts[tid - off] : 0;
        __syncthreads();
        ts[tid] += u;
        __syncthreads();
    }
    if (tid < NPG) { rp[tid] = ts[tid] - v; cur[tid] = ts[tid] - v; }
    if (tid == NPG - 1) rp[NPG] = ts[tid];
    __syncthreads();

    // scatter into per-dst runs
    for (int i = tid; i < ne; i += 256) {
        unsigned e = pair_s[i];
        int dl = e >> 18;
        int pos = atomicAdd(&cur[dl], 1);
        lsrc[pos] = e & 0x3FFFFu;
    }
    __syncthreads();

    // compute: quad (4 lanes = 4 heads) per node
    int q = tid >> 2, h = tid & 3;
    const float* asw = &prms[576];
    const float* asb = &prms[596];
    const float* adw = &prms[600];
    const float* adb = &prms[620];
    float aw[5], dw[5];
#pragma unroll
    for (int f = 0; f < 5; ++f) { aw[f] = asw[h * 5 + f]; dw[f] = adw[h * 5 + f]; }
    float ab = asb[h], db = adb[h];

    for (int nl = q; nl < NPG; nl += 64) {
        float xd[5];
#pragma unroll
        for (int f = 0; f < 5; ++f) xd[f] = xg[nl * 5 + f];
        float ad = db, as = ab;
#pragma unroll
        for (int f = 0; f < 5; ++f) { ad += dw[f] * xd[f]; as += aw[f] * xd[f]; }
        // self-loop
        float e = __expf(lrelu2(as + ad));
        float denom = e;
        float ax[5];
#pragma unroll
        for (int f = 0; f < 5; ++f) ax[f] = e * xd[f];
        // in-edges
        int b = rp[nl], en = rp[nl + 1];
        for (int i = b; i < en; ++i) {
            int s = lsrc[i];
            const float* xp = x + (size_t)s * 5;
            float xs[5];
#pragma unroll
            for (int f = 0; f < 5; ++f) xs[f] = xp[f];
            float a2 = ab;
#pragma unroll
            for (int f = 0; f < 5; ++f) a2 += aw[f] * xs[f];
            float ee = __expf(lrelu2(a2 + ad));
            denom += ee;
#pragma unroll
            for (int f = 0; f < 5; ++f) ax[f] += ee * xs[f];
        }
        float inv = 1.f / (denom + 1e-16f);
#pragma unroll
        for (int f = 0; f < 5; ++f) ax[f] *= inv;
        // expand to 24 channels, head-mean via quad shuffle, bias + ELU
        float* go = gout + ((size_t)g * NPG + nl) * 24;
#pragma unroll
        for (int c = 0; c < 24; ++c) {
            int o = h * 24 + c;
            float vv = prms[480 + o];
#pragma unroll
            for (int f = 0; f < 5; ++f) vv += prms[o * 5 + f] * ax[f];
            vv *= 0.25f;
            vv += __shfl_xor(vv, 1);
            vv += __shfl_xor(vv, 2);
            if ((c & 3) == h) {
                vv += gb[c];
                go[c] = vv > 0.f ? vv : expm1f(vv);
            }
        }
    }
}

// ---------- 5. per-graph-half Conv1d(24->8, k=62) + leaky_relu ----------
// Block = (graph, och-half of 4). 8 half-waves = 4 och x 2 row-halves (12 rows).
// Input tile XOR-swizzled: main-loop ds_read_b128 conflict-free.
// LDS = 18.8K input + 24K weights = 43.4K -> 3 blocks/CU.
__global__ __launch_bounds__(256) void conv_k(
    const float* __restrict__ gat, const float* __restrict__ wpad,
    const float* __restrict__ b, float* __restrict__ out) {
    __shared__ float it[24 * 196];      // swizzled columns
    __shared__ float wsh[4 * 24 * 64];  // this block's 4 och (reused for partials)
    int bid = blockIdx.x;
    int g = bid >> 1;
    int oh = (bid & 1) * 4;             // och base
    int tid = threadIdx.x;

    // stage input transposed + swizzled: it[c][SWZ(p)] = gat[g*186+p][c]
    for (int i = tid; i < NPG * 24; i += 256) {
        int p = i / 24, c = i % 24;
        it[c * 196 + SWZ(p)] = gat[(size_t)g * (NPG * 24) + i];
    }
    for (int i = tid; i < 24 * 6; i += 256) {     // zero pad p=186..191 (reads use p<=191)
        int c = i / 6, p = 186 + (i % 6);
        it[c * 196 + SWZ(p)] = 0.f;
    }
    // stage this block's weights
    for (int i = tid; i < 4 * 24 * 64; i += 256)
        wsh[i] = wpad[(size_t)oh * 24 * 64 + i];
    __syncthreads();

    int hw = tid >> 5;        // 0..7
    int ol = hw & 3;          // local och
    int rh = hw >> 2;         // row half
    int tt = tid & 31;
    int t0 = tt * 4;

    float a0 = 0.f, a1 = 0.f, a2 = 0.f, a3 = 0.f;
#pragma unroll
    for (int r = 0; r < 12; ++r) {
        int i = rh * 12 + r;
        const float* row = &it[i * 196];
        const float* wr = &wsh[(ol * 24 + i) * 64];
        float4 c0 = *(const float4*)&row[SWZ(t0)];
#pragma unroll
        for (int s = 0; s < 16; ++s) {
            int nx = t0 + 4 * s + 4;
            float4 c1 = *(const float4*)&row[SWZ(nx)];
            float4 wv = *(const float4*)&wr[4 * s];
            a0 += wv.x * c0.x + wv.y * c0.y + wv.z * c0.z + wv.w * c0.w;
            a1 += wv.x * c0.y + wv.y * c0.z + wv.z * c0.w + wv.w * c1.x;
            a2 += wv.x * c0.z + wv.y * c0.w + wv.z * c1.x + wv.w * c1.y;
            a3 += wv.x * c0.w + wv.y * c1.x + wv.z * c1.y + wv.w * c1.z;
            c0 = c1;
        }
    }
    __syncthreads();    // weights no longer needed; reuse wsh for partials
    *(float4*)&wsh[hw * 128 + t0] = make_float4(a0, a1, a2, a3);
    __syncthreads();
    // combine row-halves + bias + leaky_relu + store
    for (int idx = tid; idx < 4 * TOUT; idx += 256) {
        int o = idx / TOUT, t = idx - o * TOUT;
        float s = wsh[o * 128 + t] + wsh[(4 + o) * 128 + t] + b[oh + o];
        out[((size_t)g * OCH + oh + o) * TOUT + t] = s > 0.f ? s : 0.01f * s;
    }
}

extern "C" void kernel_launch(void* const* d_in, const int* in_sizes, int n_in,
                              void* d_out, int out_size, void* d_ws, size_t ws_size,
                              hipStream_t stream) {
    const float* x        = (const float*)d_in[0];
    const int*   ei       = (const int*)d_in[1];
    const float* bn_gamma = (const float*)d_in[3];
    const float* bn_beta  = (const float*)d_in[4];
    const float* lin_w    = (const float*)d_in[5];
    const float* att_src  = (const float*)d_in[6];
    const float* att_dst  = (const float*)d_in[7];
    const float* gat_bias = (const float*)d_in[8];
    const float* conv_w   = (const float*)d_in[9];
    const float* conv_b   = (const float*)d_in[10];
    float* out = (float*)d_out;
    float* wsf = (float*)d_ws;
    int*   wsi = (int*)d_ws;

    const int E = in_sizes[1] / 2;

    // ws layout (4-byte units):
    // [0..64)            stats: double sum[5]+sumsq[5]
    // [64..1088)         gcnt: 1024 ints
    // [1088..1712)       prm: 624 floats
    // [1712..14000)      wpad: 8*24*64 floats (padded conv weights)
    // [14000..)          pairbuf: 1024*4096 packed (src|dloc<<18)
    // then               gout: N*24 floats
    int*      gcnt    = wsi + 64;
    float*    prm     = wsf + 1088;
    float*    wpad    = wsf + 1712;
    unsigned* pairbuf = (unsigned*)(wsi + 14000);
    float*    gout    = (float*)(pairbuf + (size_t)NGRAPH * CAP);

    // zero stats + gcnt in one contiguous memset (4352 B)
    hipMemsetAsync(d_ws, 0, (64 + NGRAPH) * 4, stream);

    bn_stats<<<256, 256, 0, stream>>>(x, (double*)wsf);
    prep<<<1, 256, 0, stream>>>((const double*)wsf, bn_gamma, bn_beta, lin_w,
                                att_src, att_dst, conv_w, prm, wpad);
    bucket_pairs<<<NBLK, 256, 0, stream>>>(ei, E, gcnt, pairbuf);
    gat_graph<<<NGRAPH, 256, 0, stream>>>(pairbuf, gcnt, x, prm, gat_bias, gout);
    conv_k<<<NGRAPH * 2, 256, 0, stream>>>(gout, wpad, conv_b, out);
}

// Round 9
// 259.164 us; speedup vs baseline: 2.9051x; 1.3876x over previous
//
#include <hip/hip_runtime.h>
#include <hip/hip_bf16.h>
#include <math.h>

#define N_NODES 190464
#define NPG 186
#define NGRAPH 1024
#define CAP 4096
#define KW 62
#define OCH 8
#define TOUT 125
#define BCHUNK 4096
#define NBLK 744   // 744 * 4096 == 3047424 == E

// LDS column swizzle: banks for lanes 32-words apart become distinct.
// Preserves bits 0..1 (16B alignment) and stays within [0,196) for p<=191.
#define SWZ(p) ((p) ^ ((((p) >> 5) & 3) << 2))

// ---------- helpers ----------
__device__ __forceinline__ float lrelu2(float v) { return v > 0.f ? v : 0.2f * v; }

// ---------- 1. BN batch statistics: block partials, NO atomics ----------
// thread t handles 20 consecutive floats (4 nodes); f = idx % 5 static map.
// pstats layout: [10][256] doubles (f-major), block b writes column b.
__global__ __launch_bounds__(256) void bn_stats(const float* __restrict__ x,
                                                double* __restrict__ pstats) {
    __shared__ double red[10][4];
    int tid = threadIdx.x;
    int t = blockIdx.x * 256 + tid;
    const float4* xv = (const float4*)x + (size_t)t * 5;
    float4 v0 = xv[0], v1 = xv[1], v2 = xv[2], v3 = xv[3], v4 = xv[4];

    float s[5], ss[5];
    s[0] = v0.x + v1.y + v2.z + v3.w;
    s[1] = v0.y + v1.z + v2.w + v4.x;
    s[2] = v0.z + v1.w + v3.x + v4.y;
    s[3] = v0.w + v2.x + v3.y + v4.z;
    s[4] = v1.x + v2.y + v3.z + v4.w;
    ss[0] = v0.x * v0.x + v1.y * v1.y + v2.z * v2.z + v3.w * v3.w;
    ss[1] = v0.y * v0.y + v1.z * v1.z + v2.w * v2.w + v4.x * v4.x;
    ss[2] = v0.z * v0.z + v1.w * v1.w + v3.x * v3.x + v4.y * v4.y;
    ss[3] = v0.w * v0.w + v2.x * v2.x + v3.y * v3.y + v4.z * v4.z;
    ss[4] = v1.x * v1.x + v2.y * v2.y + v3.z * v3.z + v4.w * v4.w;

    double sd[5], ssd[5];
#pragma unroll
    for (int f = 0; f < 5; ++f) { sd[f] = (double)s[f]; ssd[f] = (double)ss[f]; }
#pragma unroll
    for (int f = 0; f < 5; ++f) {
        for (int off = 32; off; off >>= 1) {
            sd[f] += __shfl_down(sd[f], off);
            ssd[f] += __shfl_down(ssd[f], off);
        }
    }
    if ((tid & 63) == 0) {
        int w = tid >> 6;
#pragma unroll
        for (int f = 0; f < 5; ++f) { red[f][w] = sd[f]; red[5 + f][w] = ssd[f]; }
    }
    __syncthreads();
    if (tid < 10)
        pstats[tid * 256 + blockIdx.x] =
            red[tid][0] + red[tid][1] + red[tid][2] + red[tid][3];
}

// ---------- 2. prep: reduce partials; fold BN into lin_w; fold att; pad conv_w ----------
// prm layout (floats): wn[480]@0, hb[96]@480, as_w[20]@576, as_b[4]@596,
//                      ad_w[20]@600, ad_b[4]@620   (total 624)
__global__ void prep(const double* __restrict__ pstats,
                     const float* __restrict__ gamma,
                     const float* __restrict__ beta,
                     const float* __restrict__ lin_w,
                     const float* __restrict__ att_src,
                     const float* __restrict__ att_dst,
                     const float* __restrict__ conv_w,
                     float* __restrict__ prm,
                     float* __restrict__ wpad) {
    __shared__ double fstats[10];
    __shared__ float scale[5], shift[5];
    int t = threadIdx.x;
    int w = t >> 6, l = t & 63;
    // reduce 256 block-partials per statistic (unused slots are zero)
    for (int f = w; f < 10; f += 4) {
        const double* p = pstats + f * 256;
        double v = p[l] + p[l + 64] + p[l + 128] + p[l + 192];
        for (int off = 32; off; off >>= 1) v += __shfl_down(v, off);
        if (l == 0) fstats[f] = v;
    }
    __syncthreads();
    if (t < 5) {
        double mu = fstats[t] / (double)N_NODES;
        double var = fstats[5 + t] / (double)N_NODES - mu * mu;
        double rstd = 1.0 / sqrt(var + 1e-5);
        float sc = (float)rstd * gamma[t];
        scale[t] = sc;
        shift[t] = beta[t] - (float)mu * sc;
    }
    __syncthreads();
    if (t < 96) {
        float hbv = 0.f;
#pragma unroll
        for (int f = 0; f < 5; ++f) {
            float ww = lin_w[t * 5 + f];
            prm[t * 5 + f] = ww * scale[f];
            hbv += ww * shift[f];
        }
        prm[480 + t] = hbv;
    }
    __syncthreads();
    if (t < 8) {
        int h = t & 3;
        const float* att = (t < 4) ? att_src : att_dst;
        int wb = (t < 4) ? 576 : 600;
        int bb = (t < 4) ? 596 : 620;
        float bsum = 0.f;
        float wsum[5] = {0, 0, 0, 0, 0};
        for (int c = 0; c < 24; ++c) {
            float a = att[h * 24 + c];
            int o = h * 24 + c;
#pragma unroll
            for (int f = 0; f < 5; ++f) wsum[f] += a * prm[o * 5 + f];
            bsum += a * prm[480 + o];
        }
#pragma unroll
        for (int f = 0; f < 5; ++f) prm[wb + h * 5 + f] = wsum[f];
        prm[bb + h] = bsum;
    }
    // pad conv weights [8*24][62] -> [8*24][64] (zeros at k=62,63)
    for (int i = t; i < OCH * 24 * 64; i += 256) {
        int k = i & 63, oi = i >> 6;
        wpad[i] = (k < KW) ? conv_w[oi * KW + k] : 0.f;
    }
}

// ---------- 3. hierarchical bucket-by-graph: LDS hist -> 1 global atomic ----------
__global__ __launch_bounds__(256) void bucket_pairs(const int* __restrict__ ei,
                                                    const int E,
                                                    int* __restrict__ gcnt,
                                                    unsigned* __restrict__ pairbuf) {
    __shared__ int h[NGRAPH];
    int tid = threadIdx.x;
    int e0 = blockIdx.x * BCHUNK;
#pragma unroll
    for (int i = tid; i < NGRAPH; i += 256) h[i] = 0;
    __syncthreads();
    // pass 1: LDS histogram of dst graphs
    for (int i = tid; i < BCHUNK; i += 256) {
        int dst = ei[E + e0 + i];
        unsigned g = (unsigned)dst / NPG;
        atomicAdd(&h[g], 1);
    }
    __syncthreads();
    // reserve contiguous slots per graph with ONE global atomic each
    for (int g = tid; g < NGRAPH; g += 256) {
        int c = h[g];
        h[g] = c ? atomicAdd(&gcnt[g], c) : 0;   // h[g] becomes cursor base
    }
    __syncthreads();
    // pass 2: scatter with LDS cursors (L2-hot re-read)
    for (int i = tid; i < BCHUNK; i += 256) {
        int src = ei[e0 + i];
        int dst = ei[E + e0 + i];
        unsigned g = (unsigned)dst / NPG;
        int dloc = dst - (int)g * NPG;
        int pos = atomicAdd(&h[g], 1);
        if (pos < CAP)
            pairbuf[(size_t)g * CAP + pos] = (unsigned)src | ((unsigned)dloc << 18);
    }
}

// ---------- 4. per-graph GAT: LDS counting sort + x-space accumulation ----------
__global__ __launch_bounds__(256) void gat_graph(
    const unsigned* __restrict__ pairbuf, const int* __restrict__ gcnt,
    const float* __restrict__ x, const float* __restrict__ prm,
    const float* __restrict__ gat_bias, float* __restrict__ gout) {
    __shared__ unsigned pair_s[CAP];
    __shared__ unsigned lsrc[CAP];
    __shared__ float xg[NPG * 5];
    __shared__ int deg[188];
    __shared__ int rp[188];
    __shared__ int cur[188];
    __shared__ int ts[256];
    __shared__ float prms[624];
    __shared__ float gb[24];

    int g = blockIdx.x, tid = threadIdx.x;
    int ne = min(gcnt[g], CAP);

    for (int i = tid; i < 624; i += 256) prms[i] = prm[i];
    if (tid < 24) gb[tid] = gat_bias[tid];
    for (int i = tid; i < NPG * 5; i += 256) xg[i] = x[(size_t)g * (NPG * 5) + i];
    if (tid < 188) deg[tid] = 0;
    __syncthreads();

    // stage + histogram
    for (int i = tid; i < ne; i += 256) {
        unsigned e = pairbuf[(size_t)g * CAP + i];
        pair_s[i] = e;
        atomicAdd(&deg[e >> 18], 1);
    }
    __syncthreads();

    // exclusive scan of 186 degrees (Hillis-Steele over 256 threads)
    int v = (tid < NPG) ? deg[tid] : 0;
    ts[tid] = v;
    __syncthreads();
    for (int off = 1; off < 256; off <<= 1) {
        int u = (tid >= off) ? ts[tid - off] : 0;
        __syncthreads();
        ts[tid] += u;
        __syncthreads();
    }
    if (tid < NPG) { rp[tid] = ts[tid] - v; cur[tid] = ts[tid] - v; }
    if (tid == NPG - 1) rp[NPG] = ts[tid];
    __syncthreads();

    // scatter into per-dst runs
    for (int i = tid; i < ne; i += 256) {
        unsigned e = pair_s[i];
        int dl = e >> 18;
        int pos = atomicAdd(&cur[dl], 1);
        lsrc[pos] = e & 0x3FFFFu;
    }
    __syncthreads();

    // compute: quad (4 lanes = 4 heads) per node
    int q = tid >> 2, h = tid & 3;
    const float* asw = &prms[576];
    const float* asb = &prms[596];
    const float* adw = &prms[600];
    const float* adb = &prms[620];
    float aw[5], dw[5];
#pragma unroll
    for (int f = 0; f < 5; ++f) { aw[f] = asw[h * 5 + f]; dw[f] = adw[h * 5 + f]; }
    float ab = asb[h], db = adb[h];

    for (int nl = q; nl < NPG; nl += 64) {
        float xd[5];
#pragma unroll
        for (int f = 0; f < 5; ++f) xd[f] = xg[nl * 5 + f];
        float ad = db, as = ab;
#pragma unroll
        for (int f = 0; f < 5; ++f) { ad += dw[f] * xd[f]; as += aw[f] * xd[f]; }
        // self-loop
        float e = __expf(lrelu2(as + ad));
        float denom = e;
        float ax[5];
#pragma unroll
        for (int f = 0; f < 5; ++f) ax[f] = e * xd[f];
        // in-edges
        int b = rp[nl], en = rp[nl + 1];
        for (int i = b; i < en; ++i) {
            int s = lsrc[i];
            const float* xp = x + (size_t)s * 5;
            float xs[5];
#pragma unroll
            for (int f = 0; f < 5; ++f) xs[f] = xp[f];
            float a2 = ab;
#pragma unroll
            for (int f = 0; f < 5; ++f) a2 += aw[f] * xs[f];
            float ee = __expf(lrelu2(a2 + ad));
            denom += ee;
#pragma unroll
            for (int f = 0; f < 5; ++f) ax[f] += ee * xs[f];
        }
        float inv = 1.f / (denom + 1e-16f);
#pragma unroll
        for (int f = 0; f < 5; ++f) ax[f] *= inv;
        // expand to 24 channels, head-mean via quad shuffle, bias + ELU
        float* go = gout + ((size_t)g * NPG + nl) * 24;
#pragma unroll
        for (int c = 0; c < 24; ++c) {
            int o = h * 24 + c;
            float vv = prms[480 + o];
#pragma unroll
            for (int f = 0; f < 5; ++f) vv += prms[o * 5 + f] * ax[f];
            vv *= 0.25f;
            vv += __shfl_xor(vv, 1);
            vv += __shfl_xor(vv, 2);
            if ((c & 3) == h) {
                vv += gb[c];
                go[c] = vv > 0.f ? vv : expm1f(vv);
            }
        }
    }
}

// ---------- 5. per-graph-half Conv1d(24->8, k=62) + leaky_relu ----------
// Block = (graph, och-half of 4). 8 half-waves = 4 och x 2 row-halves (12 rows).
// Input tile XOR-swizzled: main-loop ds_read_b128 conflict-free.
// LDS = 18.8K input + 24K weights = 43.4K -> 3 blocks/CU.
__global__ __launch_bounds__(256) void conv_k(
    const float* __restrict__ gat, const float* __restrict__ wpad,
    const float* __restrict__ b, float* __restrict__ out) {
    __shared__ float it[24 * 196];      // swizzled columns
    __shared__ float wsh[4 * 24 * 64];  // this block's 4 och (reused for partials)
    int bid = blockIdx.x;
    int g = bid >> 1;
    int oh = (bid & 1) * 4;             // och base
    int tid = threadIdx.x;

    // stage input transposed + swizzled: it[c][SWZ(p)] = gat[g*186+p][c]
    for (int i = tid; i < NPG * 24; i += 256) {
        int p = i / 24, c = i % 24;
        it[c * 196 + SWZ(p)] = gat[(size_t)g * (NPG * 24) + i];
    }
    for (int i = tid; i < 24 * 6; i += 256) {     // zero pad p=186..191 (reads use p<=191)
        int c = i / 6, p = 186 + (i % 6);
        it[c * 196 + SWZ(p)] = 0.f;
    }
    // stage this block's weights
    for (int i = tid; i < 4 * 24 * 64; i += 256)
        wsh[i] = wpad[(size_t)oh * 24 * 64 + i];
    __syncthreads();

    int hw = tid >> 5;        // 0..7
    int ol = hw & 3;          // local och
    int rh = hw >> 2;         // row half
    int tt = tid & 31;
    int t0 = tt * 4;

    float a0 = 0.f, a1 = 0.f, a2 = 0.f, a3 = 0.f;
#pragma unroll
    for (int r = 0; r < 12; ++r) {
        int i = rh * 12 + r;
        const float* row = &it[i * 196];
        const float* wr = &wsh[(ol * 24 + i) * 64];
        float4 c0 = *(const float4*)&row[SWZ(t0)];
#pragma unroll
        for (int s = 0; s < 16; ++s) {
            int nx = t0 + 4 * s + 4;
            float4 c1 = *(const float4*)&row[SWZ(nx)];
            float4 wv = *(const float4*)&wr[4 * s];
            a0 += wv.x * c0.x + wv.y * c0.y + wv.z * c0.z + wv.w * c0.w;
            a1 += wv.x * c0.y + wv.y * c0.z + wv.z * c0.w + wv.w * c1.x;
            a2 += wv.x * c0.z + wv.y * c0.w + wv.z * c1.x + wv.w * c1.y;
            a3 += wv.x * c0.w + wv.y * c1.x + wv.z * c1.y + wv.w * c1.z;
            c0 = c1;
        }
    }
    __syncthreads();    // weights no longer needed; reuse wsh for partials
    *(float4*)&wsh[hw * 128 + t0] = make_float4(a0, a1, a2, a3);
    __syncthreads();
    // combine row-halves + bias + leaky_relu + store
    for (int idx = tid; idx < 4 * TOUT; idx += 256) {
        int o = idx / TOUT, t = idx - o * TOUT;
        float s = wsh[o * 128 + t] + wsh[(4 + o) * 128 + t] + b[oh + o];
        out[((size_t)g * OCH + oh + o) * TOUT + t] = s > 0.f ? s : 0.01f * s;
    }
}

extern "C" void kernel_launch(void* const* d_in, const int* in_sizes, int n_in,
                              void* d_out, int out_size, void* d_ws, size_t ws_size,
                              hipStream_t stream) {
    const float* x        = (const float*)d_in[0];
    const int*   ei       = (const int*)d_in[1];
    const float* bn_gamma = (const float*)d_in[3];
    const float* bn_beta  = (const float*)d_in[4];
    const float* lin_w    = (const float*)d_in[5];
    const float* att_src  = (const float*)d_in[6];
    const float* att_dst  = (const float*)d_in[7];
    const float* gat_bias = (const float*)d_in[8];
    const float* conv_w   = (const float*)d_in[9];
    const float* conv_b   = (const float*)d_in[10];
    float* out = (float*)d_out;
    float* wsf = (float*)d_ws;
    int*   wsi = (int*)d_ws;

    const int E = in_sizes[1] / 2;

    // ws layout (4-byte units):
    // [0..1024)          gcnt: 1024 ints                 (zeroed)
    // [1024..6144)       pstats: 10*256 doubles          (zeroed; 8B-aligned)
    // [6144..6768)       prm: 624 floats
    // [6768..19056)      wpad: 8*24*64 floats
    // [19056..)          pairbuf: 1024*4096 packed (src|dloc<<18)
    // then               gout: N*24 floats
    int*      gcnt    = wsi;
    double*   pstats  = (double*)(wsf + 1024);
    float*    prm     = wsf + 6144;
    float*    wpad    = wsf + 6768;
    unsigned* pairbuf = (unsigned*)(wsi + 19056);
    float*    gout    = (float*)(pairbuf + (size_t)NGRAPH * CAP);

    // zero gcnt + pstats in one contiguous memset (24576 B)
    hipMemsetAsync(d_ws, 0, 6144 * 4, stream);

    bn_stats<<<186, 256, 0, stream>>>(x, pstats);
    prep<<<1, 256, 0, stream>>>(pstats, bn_gamma, bn_beta, lin_w,
                                att_src, att_dst, conv_w, prm, wpad);
    bucket_pairs<<<NBLK, 256, 0, stream>>>(ei, E, gcnt, pairbuf);
    gat_graph<<<NGRAPH, 256, 0, stream>>>(pairbuf, gcnt, x, prm, gat_bias, gout);
    conv_k<<<NGRAPH * 2, 256, 0, stream>>>(gout, wpad, conv_b, out);
}